// Round 6
// baseline (373.203 us; speedup 1.0000x reference)
//
#include <hip/hip_runtime.h>
#include <hip/hip_bf16.h>

#define BB 2
#define SS 2048
#define DIMM 1024
#define HH 16
#define DKK 64
// 0.125 (1/sqrt(DK)) * log2(e): folded into Q so softmax uses raw v_exp_f32 (2^x)
#define QSCALE 0.18033688011112042592f

using bf16 = __hip_bfloat16;
typedef __attribute__((ext_vector_type(8))) short v8s;
typedef __attribute__((ext_vector_type(4))) float f32x4;

__device__ __forceinline__ float b2f(bf16 x) { return __bfloat162float(x); }

// ---------------------------------------------------------------------------
// MFMA GEMM: C = A @ W^T.  A [4096,1024] (fp32 or bf16 per A_BF16),
// W [N,1024] fp32.  128x128 tile, 4 waves, 4x4 16x16x32 frags/wave, BK=64.
// MODE 0: Q epilogue  -> out0[b,h,s,d] bf16 (h=n&15, d=n>>4), PRESCALED
// MODE 1: KV epilogue -> K like MODE 0 (no prescale); V transposed [b,h,d,s]
// MODE 2: plain fp32  -> out2[m*1024+n]
// ---------------------------------------------------------------------------
template <int MODE, bool A_BF16>
__global__ __launch_bounds__(256) void mfma_gemm_kernel(
    const void* __restrict__ Ag, const float* __restrict__ Wg,
    bf16* __restrict__ out0, bf16* __restrict__ out1,
    float* __restrict__ out2) {
  __shared__ __align__(16) bf16 As[128][72];
  __shared__ __align__(16) bf16 Bs[128][72];
  const int t = threadIdx.x;
  const int wave = t >> 6, lane = t & 63;
  const int quad = lane >> 4, l15 = lane & 15;
  const int wm = (wave >> 1) * 64, wn = (wave & 1) * 64;
  const int n0 = blockIdx.x * 128;
  const int m0 = blockIdx.y * 128;

  const int sr = t >> 2;        // staging row 0..63 (and +64)
  const int sc = (t & 3) * 16;  // staging col segment (16 elems)

  f32x4 acc[4][4] = {};

  for (int kc = 0; kc < DIMM; kc += 64) {
    __syncthreads();
    // ---- stage A tile (128 x 64) as bf16 ----
    if (A_BF16) {
      const bf16* Ab = (const bf16*)Ag;
#pragma unroll
      for (int rr = 0; rr < 2; ++rr) {
        const int r = sr + rr * 64;
        const bf16* p = Ab + (size_t)(m0 + r) * DIMM + kc + sc;
        *(v8s*)&As[r][sc] = *(const v8s*)p;
        *(v8s*)&As[r][sc + 8] = *(const v8s*)(p + 8);
      }
    } else {
      const float* Af = (const float*)Ag;
#pragma unroll
      for (int rr = 0; rr < 2; ++rr) {
        const int r = sr + rr * 64;
        const float* p = Af + (size_t)(m0 + r) * DIMM + kc + sc;
        bf16 tmp[16];
#pragma unroll
        for (int j = 0; j < 16; ++j) tmp[j] = __float2bfloat16(p[j]);
        *(v8s*)&As[r][sc] = *(const v8s*)&tmp[0];
        *(v8s*)&As[r][sc + 8] = *(const v8s*)&tmp[8];
      }
    }
    // ---- stage W tile (128 x 64) as bf16 ----
#pragma unroll
    for (int rr = 0; rr < 2; ++rr) {
      const int r = sr + rr * 64;
      const float* p = Wg + (size_t)(n0 + r) * DIMM + kc + sc;
      bf16 tmp[16];
#pragma unroll
      for (int j = 0; j < 16; ++j) tmp[j] = __float2bfloat16(p[j]);
      *(v8s*)&Bs[r][sc] = *(const v8s*)&tmp[0];
      *(v8s*)&Bs[r][sc + 8] = *(const v8s*)&tmp[8];
    }
    __syncthreads();

#pragma unroll
    for (int ks = 0; ks < 2; ++ks) {
      v8s af[4], bfr[4];
#pragma unroll
      for (int i = 0; i < 4; ++i)
        af[i] = *(const v8s*)&As[wm + i * 16 + l15][ks * 32 + quad * 8];
#pragma unroll
      for (int j = 0; j < 4; ++j)
        bfr[j] = *(const v8s*)&Bs[wn + j * 16 + l15][ks * 32 + quad * 8];
#pragma unroll
      for (int i = 0; i < 4; ++i)
#pragma unroll
        for (int j = 0; j < 4; ++j)
          acc[i][j] = __builtin_amdgcn_mfma_f32_16x16x32_bf16(
              af[i], bfr[j], acc[i][j], 0, 0, 0);
    }
  }

  // ---- epilogue ----
#pragma unroll
  for (int i = 0; i < 4; ++i) {
#pragma unroll
    for (int r = 0; r < 4; ++r) {
      const int m = m0 + wm + i * 16 + quad * 4 + r;
      const int b = m >> 11, s = m & (SS - 1);
#pragma unroll
      for (int j = 0; j < 4; ++j) {
        const int n = n0 + wn + j * 16 + l15;
        const float v = acc[i][j][r];
        if (MODE == 2) {
          out2[(size_t)m * DIMM + n] = v;
        } else if (MODE == 0) {
          const int h = n & 15, d = n >> 4;
          out0[(((size_t)b * HH + h) * SS + s) * DKK + d] =
              __float2bfloat16(v * QSCALE);
        } else {
          if (n < DIMM) {
            const int h = n & 15, d = n >> 4;
            out0[(((size_t)b * HH + h) * SS + s) * DKK + d] =
                __float2bfloat16(v);
          } else {
            const int nn = n - DIMM;
            const int h = nn & 15, d = nn >> 4;
            out1[(((size_t)b * HH + h) * DKK + d) * SS + s] =
                __float2bfloat16(v);
          }
        }
      }
    }
  }
}

// ---------------------------------------------------------------------------
// MFMA flash attention, static-max softmax, FUSED raw-mask read (int32),
// XCD-swizzled blocks, register-prefetch pipeline (unroll-by-2 A/B sets).
// Block = 64 q rows (4 waves x 16), K-tiles of 64.
// Qr,Kr: [B,H,S,64] bf16 (Q prescaled by 0.125*log2e).  Vt: [B,H,64,S] bf16.
// Ar bf16 [B,S,DIM] (q, d*16+h).
// ---------------------------------------------------------------------------
struct PF {
  v8s k0, k1, v0, v1;
  int m[16];
};

__global__ __launch_bounds__(256) void attn_kernel(
    const bf16* __restrict__ Qr, const bf16* __restrict__ Kr,
    const bf16* __restrict__ Vt, const int* __restrict__ mask,
    bf16* __restrict__ Ar) {
  __shared__ __align__(16) bf16 Ks[64][72];
  __shared__ __align__(16) bf16 Vs[64][72];   // Vs[d][kk]
  __shared__ __align__(16) bf16 Ps[4][16][72];

  const int t = threadIdx.x;
  const int wave = t >> 6, lane = t & 63;
  const int quad = lane >> 4, l15 = lane & 15;

  // XCD swizzle: all 32 q-tiles of one (b,h) land on the same XCD (bx % 8).
  const int bx = blockIdx.x;
  const int xcd = bx & 7, j = bx >> 3;
  const int g = (xcd << 2) | (j & 3);   // (b,h) group 0..31
  const int tile = j >> 2;              // q-tile 0..31
  const int h = g & 15, b = g >> 4;

  const int qw = tile * 64 + wave * 16;
  const size_t bh = ((size_t)b * HH + h) * SS;
  const bf16* Kr_bh = Kr + bh * DKK;
  const bf16* Vt_bh = Vt + ((size_t)b * HH + h) * DKK * SS;

  // Q A-frags (resident whole kernel)
  const v8s aq0 = *(const v8s*)(Qr + (bh + qw + l15) * DKK + quad * 8);
  const v8s aq1 = *(const v8s*)(Qr + (bh + qw + l15) * DKK + 32 + quad * 8);

  // raw-mask row pointers for the 4 q-rows this lane's quad owns
  const int* mrow[4];
#pragma unroll
  for (int r = 0; r < 4; ++r)
    mrow[r] = mask + ((size_t)b * SS + qw + quad * 4 + r) * SS + l15;

  f32x4 o[4] = {};
  float lsum[4] = {0.f, 0.f, 0.f, 0.f};

  const int id0 = t * 8;
  const int r0 = id0 >> 6, c0 = id0 & 63;  // staging coords

  auto issue_kv = [&](PF& nx, int k0) {
    nx.k0 = *(const v8s*)(Kr_bh + (size_t)(k0 + r0) * DKK + c0);
    nx.k1 = *(const v8s*)(Kr_bh + (size_t)(k0 + r0 + 32) * DKK + c0);
    nx.v0 = *(const v8s*)(Vt_bh + (size_t)r0 * SS + k0 + c0);
    nx.v1 = *(const v8s*)(Vt_bh + (size_t)(r0 + 32) * SS + k0 + c0);
  };
  auto issue_mask = [&](PF& nx, int k0) {
#pragma unroll
    for (int r = 0; r < 4; ++r)
#pragma unroll
      for (int n = 0; n < 4; ++n)
        nx.m[r * 4 + n] = __builtin_nontemporal_load(mrow[r] + k0 + n * 16);
  };

  auto step = [&](PF& cur, PF& nx, int kt) {
    const int kn = (kt < 31 ? kt + 1 : 31) * 64;  // clamped prefetch tile
    __syncthreads();
    *(v8s*)&Ks[r0][c0] = cur.k0;
    *(v8s*)&Ks[r0 + 32][c0] = cur.k1;
    *(v8s*)&Vs[r0][c0] = cur.v0;
    *(v8s*)&Vs[r0 + 32][c0] = cur.v1;
    issue_kv(nx, kn);
    __syncthreads();

    // QK^T: 4 key-subtiles of 16
    f32x4 sc[4];
#pragma unroll
    for (int n = 0; n < 4; ++n) {
      const v8s bk0 = *(const v8s*)&Ks[n * 16 + l15][quad * 8];
      const v8s bk1 = *(const v8s*)&Ks[n * 16 + l15][32 + quad * 8];
      f32x4 z = {0.f, 0.f, 0.f, 0.f};
      z = __builtin_amdgcn_mfma_f32_16x16x32_bf16(aq0, bk0, z, 0, 0, 0);
      sc[n] = __builtin_amdgcn_mfma_f32_16x16x32_bf16(aq1, bk1, z, 0, 0, 0);
    }

    // p = mask ? 2^sc : 0 ; per-lane denom partials
#pragma unroll
    for (int n = 0; n < 4; ++n)
#pragma unroll
      for (int r = 0; r < 4; ++r) {
        const float p =
            cur.m[r * 4 + n] ? __builtin_amdgcn_exp2f(sc[n][r]) : 0.f;
        sc[n][r] = p;
        lsum[r] += p;
      }

    issue_mask(nx, kn);  // mask for next tile: latency hidden under P/V phase

    // P: C-layout -> LDS -> A-layout (per-wave region, in-wave dependency)
#pragma unroll
    for (int n = 0; n < 4; ++n)
#pragma unroll
      for (int r = 0; r < 4; ++r)
        Ps[wave][quad * 4 + r][n * 16 + l15] = __float2bfloat16(sc[n][r]);
    const v8s ap0 = *(const v8s*)&Ps[wave][l15][quad * 8];
    const v8s ap1 = *(const v8s*)&Ps[wave][l15][32 + quad * 8];

    // PV (d-subtiles of 16)
#pragma unroll
    for (int n = 0; n < 4; ++n) {
      const v8s bv0 = *(const v8s*)&Vs[n * 16 + l15][quad * 8];
      const v8s bv1 = *(const v8s*)&Vs[n * 16 + l15][32 + quad * 8];
      o[n] = __builtin_amdgcn_mfma_f32_16x16x32_bf16(ap0, bv0, o[n], 0, 0, 0);
      o[n] = __builtin_amdgcn_mfma_f32_16x16x32_bf16(ap1, bv1, o[n], 0, 0, 0);
    }
  };

  PF A, B;
  issue_kv(A, 0);
  issue_mask(A, 0);
  for (int kt = 0; kt < 32; kt += 2) {
    step(A, B, kt);
    step(B, A, kt + 1);
  }

  // epilogue: reduce denom across the 16 lanes holding each row, store
#pragma unroll
  for (int r = 0; r < 4; ++r) {
    float l = lsum[r];
    l += __shfl_xor(l, 1);
    l += __shfl_xor(l, 2);
    l += __shfl_xor(l, 4);
    l += __shfl_xor(l, 8);
    const float inv = 1.f / l;
    const size_t row = (size_t)b * SS + qw + quad * 4 + r;
#pragma unroll
    for (int n = 0; n < 4; ++n) {
      const int d = n * 16 + l15;
      Ar[row * DIMM + d * 16 + h] = __float2bfloat16(o[n][r] * inv);
    }
  }
}

extern "C" void kernel_launch(void* const* d_in, const int* in_sizes, int n_in,
                              void* d_out, int out_size, void* d_ws,
                              size_t ws_size, hipStream_t stream) {
  const float* dec = (const float*)d_in[0];
  const float* enc = (const float*)d_in[1];
  const float* Wq = (const float*)d_in[2];
  const float* Wkv = (const float*)d_in[3];
  const float* Wo = (const float*)d_in[4];
  const int* mask = (const int*)d_in[5];
  float* out = (float*)d_out;

  char* ws = (char*)d_ws;
  bf16* Qr = (bf16*)ws;                               // 8 MB [B,H,S,64]
  bf16* Kr = (bf16*)(ws + ((size_t)8 << 20));         // 8 MB [B,H,S,64]
  bf16* Vt = (bf16*)(ws + ((size_t)16 << 20));        // 8 MB [B,H,64,S]
  bf16* Ar = (bf16*)(ws + ((size_t)24 << 20));        // 8 MB [B,S,DIM]

  dim3 blk(256);
  mfma_gemm_kernel<0, false>
      <<<dim3(8, 32), blk, 0, stream>>>(dec, Wq, Qr, nullptr, nullptr);
  mfma_gemm_kernel<1, false>
      <<<dim3(16, 32), blk, 0, stream>>>(enc, Wkv, Kr, Vt, nullptr);
  attn_kernel<<<dim3(1024), blk, 0, stream>>>(Qr, Kr, Vt, mask, Ar);
  mfma_gemm_kernel<2, true>
      <<<dim3(8, 32), blk, 0, stream>>>(Ar, Wo, nullptr, nullptr, out);
}

// Round 7
// 330.067 us; speedup vs baseline: 1.1307x; 1.1307x over previous
//
#include <hip/hip_runtime.h>
#include <hip/hip_bf16.h>

#define BB 2
#define SS 2048
#define DIMM 1024
#define HH 16
#define DKK 64
// 0.125 (1/sqrt(DK)) * log2(e): folded into Q so softmax uses raw v_exp_f32 (2^x)
#define QSCALE 0.18033688011112042592f

using bf16 = __hip_bfloat16;
typedef __attribute__((ext_vector_type(8))) short v8s;
typedef __attribute__((ext_vector_type(4))) short v4s;
typedef __attribute__((ext_vector_type(4))) float f32x4;

__device__ __forceinline__ float b2f(bf16 x) { return __bfloat162float(x); }

__device__ __forceinline__ void cvt4(const float* __restrict__ s,
                                     bf16* __restrict__ d, int idx) {
  const float4 f = ((const float4*)s)[idx];
  bf16 t[4] = {__float2bfloat16(f.x), __float2bfloat16(f.y),
               __float2bfloat16(f.z), __float2bfloat16(f.w)};
  *(v4s*)(d + (size_t)idx * 4) = *(const v4s*)t;
}

// ---------------------------------------------------------------------------
// Fused fp32->bf16 conversion (enc, Wkv, Wo) + mask bit-packing.
// Grid: 1024 x 256 (262144 threads, 4096 waves).
// ---------------------------------------------------------------------------
__global__ __launch_bounds__(256) void convert_pack_kernel(
    const float* __restrict__ enc, const float* __restrict__ Wkv,
    const float* __restrict__ Wo, const int* __restrict__ mask,
    bf16* __restrict__ encb, bf16* __restrict__ Wkvb, bf16* __restrict__ Wob,
    unsigned long long* __restrict__ mp) {
  const int gid = blockIdx.x * 256 + threadIdx.x;  // 0..262143
  const int NT = 256 * 1024;
  // enc: 4.19M floats = 1,048,576 float4 chunks
#pragma unroll
  for (int i = 0; i < 4; ++i) cvt4(enc, encb, gid + i * NT);
  // Wkv: 2.10M floats = 524,288 chunks
#pragma unroll
  for (int i = 0; i < 2; ++i) cvt4(Wkv, Wkvb, gid + i * NT);
  // Wo: 1.05M floats = 262,144 chunks
  cvt4(Wo, Wob, gid);
  // mask pack: mp[row*32+kt] bit c = mask[row*2048 + kt*64 + c]
  const int lane = threadIdx.x & 63;
  const int wave_id = gid >> 6;  // 0..4095
  for (int i = 0; i < 32; ++i) {
    const size_t w = (size_t)wave_id * 32 + i;
    const unsigned long long bm = __ballot(mask[w * 64 + lane] != 0);
    if (lane == 0) mp[w] = bm;
  }
}

// ---------------------------------------------------------------------------
// MFMA GEMM: C = A @ W^T.  128x128 tile, 4 waves, 4x4 16x16x32 frags, BK=64.
// A_BF16 / W_BF16 select staging path (bf16 = straight v8s copy, no cvt).
// MODE 0: Q epilogue  -> out0[b,h,s,d] bf16 (h=n&15, d=n>>4), PRESCALED
// MODE 1: KV epilogue -> K like MODE 0 (no prescale); V transposed [b,h,d,s]
// MODE 2: plain fp32  -> out2[m*1024+n]
// ---------------------------------------------------------------------------
template <int MODE, bool A_BF16, bool W_BF16>
__global__ __launch_bounds__(256) void mfma_gemm_kernel(
    const void* __restrict__ Ag, const void* __restrict__ Wg,
    bf16* __restrict__ out0, bf16* __restrict__ out1,
    float* __restrict__ out2) {
  __shared__ __align__(16) bf16 As[128][72];
  __shared__ __align__(16) bf16 Bs[128][72];
  const int t = threadIdx.x;
  const int wave = t >> 6, lane = t & 63;
  const int quad = lane >> 4, l15 = lane & 15;
  const int wm = (wave >> 1) * 64, wn = (wave & 1) * 64;
  const int n0 = blockIdx.x * 128;
  const int m0 = blockIdx.y * 128;

  const int sr = t >> 2;        // staging row 0..63 (and +64)
  const int sc = (t & 3) * 16;  // staging col segment (16 elems)

  f32x4 acc[4][4] = {};

  for (int kc = 0; kc < DIMM; kc += 64) {
    __syncthreads();
    // ---- stage A tile (128 x 64) ----
#pragma unroll
    for (int rr = 0; rr < 2; ++rr) {
      const int r = sr + rr * 64;
      if (A_BF16) {
        const bf16* p = (const bf16*)Ag + (size_t)(m0 + r) * DIMM + kc + sc;
        *(v8s*)&As[r][sc] = *(const v8s*)p;
        *(v8s*)&As[r][sc + 8] = *(const v8s*)(p + 8);
      } else {
        const float* p = (const float*)Ag + (size_t)(m0 + r) * DIMM + kc + sc;
        bf16 tmp[16];
#pragma unroll
        for (int j = 0; j < 16; ++j) tmp[j] = __float2bfloat16(p[j]);
        *(v8s*)&As[r][sc] = *(const v8s*)&tmp[0];
        *(v8s*)&As[r][sc + 8] = *(const v8s*)&tmp[8];
      }
    }
    // ---- stage W tile (128 x 64) ----
#pragma unroll
    for (int rr = 0; rr < 2; ++rr) {
      const int r = sr + rr * 64;
      if (W_BF16) {
        const bf16* p = (const bf16*)Wg + (size_t)(n0 + r) * DIMM + kc + sc;
        *(v8s*)&Bs[r][sc] = *(const v8s*)p;
        *(v8s*)&Bs[r][sc + 8] = *(const v8s*)(p + 8);
      } else {
        const float* p = (const float*)Wg + (size_t)(n0 + r) * DIMM + kc + sc;
        bf16 tmp[16];
#pragma unroll
        for (int j = 0; j < 16; ++j) tmp[j] = __float2bfloat16(p[j]);
        *(v8s*)&Bs[r][sc] = *(const v8s*)&tmp[0];
        *(v8s*)&Bs[r][sc + 8] = *(const v8s*)&tmp[8];
      }
    }
    __syncthreads();

#pragma unroll
    for (int ks = 0; ks < 2; ++ks) {
      v8s af[4], bfr[4];
#pragma unroll
      for (int i = 0; i < 4; ++i)
        af[i] = *(const v8s*)&As[wm + i * 16 + l15][ks * 32 + quad * 8];
#pragma unroll
      for (int j = 0; j < 4; ++j)
        bfr[j] = *(const v8s*)&Bs[wn + j * 16 + l15][ks * 32 + quad * 8];
#pragma unroll
      for (int i = 0; i < 4; ++i)
#pragma unroll
        for (int j = 0; j < 4; ++j)
          acc[i][j] = __builtin_amdgcn_mfma_f32_16x16x32_bf16(
              af[i], bfr[j], acc[i][j], 0, 0, 0);
    }
  }

  // ---- epilogue ----
#pragma unroll
  for (int i = 0; i < 4; ++i) {
#pragma unroll
    for (int r = 0; r < 4; ++r) {
      const int m = m0 + wm + i * 16 + quad * 4 + r;
      const int b = m >> 11, s = m & (SS - 1);
#pragma unroll
      for (int j = 0; j < 4; ++j) {
        const int n = n0 + wn + j * 16 + l15;
        const float v = acc[i][j][r];
        if (MODE == 2) {
          out2[(size_t)m * DIMM + n] = v;
        } else if (MODE == 0) {
          const int h = n & 15, d = n >> 4;
          out0[(((size_t)b * HH + h) * SS + s) * DKK + d] =
              __float2bfloat16(v * QSCALE);
        } else {
          if (n < DIMM) {
            const int h = n & 15, d = n >> 4;
            out0[(((size_t)b * HH + h) * SS + s) * DKK + d] =
                __float2bfloat16(v);
          } else {
            const int nn = n - DIMM;
            const int h = nn & 15, d = nn >> 4;
            out1[(((size_t)b * HH + h) * DKK + d) * SS + s] =
                __float2bfloat16(v);
          }
        }
      }
    }
  }
}

// ---------------------------------------------------------------------------
// MFMA flash attention, static-max softmax, packed u64 mask, XCD swizzle.
// Block = 64 q rows (4 waves x 16), K-tiles of 64.  Round-5 body (VGPR-lean).
// Qr,Kr: [B,H,S,64] bf16 (Q prescaled).  Vt: [B,H,64,S] bf16.
// Ar bf16 [B,S,DIM] (q, d*16+h).
// ---------------------------------------------------------------------------
__global__ __launch_bounds__(256) void attn_kernel(
    const bf16* __restrict__ Qr, const bf16* __restrict__ Kr,
    const bf16* __restrict__ Vt, const unsigned long long* __restrict__ mp,
    bf16* __restrict__ Ar) {
  __shared__ __align__(16) bf16 Ks[64][72];
  __shared__ __align__(16) bf16 Vs[64][72];   // Vs[d][kk]
  __shared__ __align__(16) bf16 Ps[4][16][72];

  const int t = threadIdx.x;
  const int wave = t >> 6, lane = t & 63;
  const int quad = lane >> 4, l15 = lane & 15;

  // XCD swizzle: all 32 q-tiles of one (b,h) land on the same XCD (bx % 8).
  const int bx = blockIdx.x;
  const int xcd = bx & 7, j = bx >> 3;
  const int g = (xcd << 2) | (j & 3);   // (b,h) group 0..31
  const int tile = j >> 2;              // q-tile 0..31
  const int h = g & 15, b = g >> 4;

  const int qw = tile * 64 + wave * 16;
  const size_t bh = ((size_t)b * HH + h) * SS;
  const size_t bhv = ((size_t)b * HH + h) * DKK;

  const v8s aq0 = *(const v8s*)(Qr + (bh + qw + l15) * DKK + quad * 8);
  const v8s aq1 = *(const v8s*)(Qr + (bh + qw + l15) * DKK + 32 + quad * 8);

  f32x4 o[4] = {};
  float lsum[4] = {0.f, 0.f, 0.f, 0.f};

  const int id0 = t * 8;
  const int r0 = id0 >> 6, c0 = id0 & 63;

  for (int kt = 0; kt < 32; ++kt) {
    const int k0 = kt * 64;
    __syncthreads();
    *(v8s*)&Ks[r0][c0]      = *(const v8s*)(Kr + (bh + k0 + r0) * DKK + c0);
    *(v8s*)&Ks[r0 + 32][c0] = *(const v8s*)(Kr + (bh + k0 + r0 + 32) * DKK + c0);
    *(v8s*)&Vs[r0][c0]      = *(const v8s*)(Vt + (bhv + r0) * SS + k0 + c0);
    *(v8s*)&Vs[r0 + 32][c0] = *(const v8s*)(Vt + (bhv + r0 + 32) * SS + k0 + c0);
    __syncthreads();

    // QK^T (Q prescaled): 4 key-subtiles of 16
    f32x4 sc[4];
#pragma unroll
    for (int n = 0; n < 4; ++n) {
      const v8s bk0 = *(const v8s*)&Ks[n * 16 + l15][quad * 8];
      const v8s bk1 = *(const v8s*)&Ks[n * 16 + l15][32 + quad * 8];
      f32x4 z = {0.f, 0.f, 0.f, 0.f};
      z = __builtin_amdgcn_mfma_f32_16x16x32_bf16(aq0, bk0, z, 0, 0, 0);
      sc[n] = __builtin_amdgcn_mfma_f32_16x16x32_bf16(aq1, bk1, z, 0, 0, 0);
    }

    // p = mask ? 2^sc : 0 ; per-lane denom partials
    unsigned long long mw[4];
#pragma unroll
    for (int r = 0; r < 4; ++r)
      mw[r] = mp[((size_t)b * SS + qw + quad * 4 + r) * 32 + kt];
#pragma unroll
    for (int n = 0; n < 4; ++n)
#pragma unroll
      for (int r = 0; r < 4; ++r) {
        const bool keep = (mw[r] >> (n * 16 + l15)) & 1ULL;
        const float p = keep ? __builtin_amdgcn_exp2f(sc[n][r]) : 0.f;
        sc[n][r] = p;
        lsum[r] += p;
      }

    // P: C-layout -> LDS -> A-layout (per-wave region, in-wave dependency)
#pragma unroll
    for (int n = 0; n < 4; ++n)
#pragma unroll
      for (int r = 0; r < 4; ++r)
        Ps[wave][quad * 4 + r][n * 16 + l15] = __float2bfloat16(sc[n][r]);
    const v8s ap0 = *(const v8s*)&Ps[wave][l15][quad * 8];
    const v8s ap1 = *(const v8s*)&Ps[wave][l15][32 + quad * 8];

    // PV (d-subtiles of 16)
#pragma unroll
    for (int n = 0; n < 4; ++n) {
      const v8s bv0 = *(const v8s*)&Vs[n * 16 + l15][quad * 8];
      const v8s bv1 = *(const v8s*)&Vs[n * 16 + l15][32 + quad * 8];
      o[n] = __builtin_amdgcn_mfma_f32_16x16x32_bf16(ap0, bv0, o[n], 0, 0, 0);
      o[n] = __builtin_amdgcn_mfma_f32_16x16x32_bf16(ap1, bv1, o[n], 0, 0, 0);
    }
  }

  // epilogue: reduce denom across the 16 lanes holding each row, store
#pragma unroll
  for (int r = 0; r < 4; ++r) {
    float l = lsum[r];
    l += __shfl_xor(l, 1);
    l += __shfl_xor(l, 2);
    l += __shfl_xor(l, 4);
    l += __shfl_xor(l, 8);
    const float inv = 1.f / l;
    const size_t row = (size_t)b * SS + qw + quad * 4 + r;
#pragma unroll
    for (int n = 0; n < 4; ++n) {
      const int d = n * 16 + l15;
      Ar[row * DIMM + d * 16 + h] = __float2bfloat16(o[n][r] * inv);
    }
  }
}

extern "C" void kernel_launch(void* const* d_in, const int* in_sizes, int n_in,
                              void* d_out, int out_size, void* d_ws,
                              size_t ws_size, hipStream_t stream) {
  const float* dec = (const float*)d_in[0];
  const float* enc = (const float*)d_in[1];
  const float* Wq = (const float*)d_in[2];
  const float* Wkv = (const float*)d_in[3];
  const float* Wo = (const float*)d_in[4];
  const int* mask = (const int*)d_in[5];
  float* out = (float*)d_out;

  // ws layout (<= 39.4 MB; Ar overlays encb — disjoint lifetimes):
  //  [0, 8.4M):    encb bf16  (live: convert -> KV-GEMM)   then Ar (attn -> out-GEMM)
  //  [8.4M,12.4M): Wkvb bf16
  //  [12.4M,14.4M):Wob  bf16
  //  [14.4M,22.4M):Qr   [B,H,S,64]
  //  [22.4M,30.4M):Kr   [B,H,S,64]
  //  [30.4M,38.4M):Vt   [B,H,64,S]
  //  [38.4M,39.4M):mp   u64 packed mask
  char* ws = (char*)d_ws;
  bf16* encb = (bf16*)ws;
  bf16* Ar = (bf16*)ws;  // overlays encb (encb dead before attn writes Ar)
  bf16* Wkvb = (bf16*)(ws + ((size_t)2 * SS * DIMM * 2));            // 8.4 MB
  bf16* Wob = (bf16*)(ws + ((size_t)2 * SS * DIMM * 2 + 4 << 20) + 0);
  // compute offsets explicitly to avoid arithmetic slips:
  size_t off = (size_t)2 * SS * DIMM * 2;          // 8,388,608  (encb)
  Wkvb = (bf16*)(ws + off);  off += (size_t)2 * DIMM * DIMM * 2;  // 4 MB
  Wob  = (bf16*)(ws + off);  off += (size_t)DIMM * DIMM * 2;      // 2 MB
  bf16* Qr = (bf16*)(ws + off); off += (size_t)2 * SS * DIMM * 2; // 8 MB
  bf16* Kr = (bf16*)(ws + off); off += (size_t)2 * SS * DIMM * 2; // 8 MB
  bf16* Vt = (bf16*)(ws + off); off += (size_t)2 * SS * DIMM * 2; // 8 MB
  unsigned long long* mp = (unsigned long long*)(ws + off);       // 1 MB

  dim3 blk(256);
  convert_pack_kernel<<<dim3(1024), blk, 0, stream>>>(enc, Wkv, Wo, mask, encb,
                                                      Wkvb, Wob, mp);
  mfma_gemm_kernel<0, false, false>
      <<<dim3(8, 32), blk, 0, stream>>>(dec, Wq, Qr, nullptr, nullptr);
  mfma_gemm_kernel<1, true, true>
      <<<dim3(16, 32), blk, 0, stream>>>(encb, Wkvb, Kr, Vt, nullptr);
  attn_kernel<<<dim3(1024), blk, 0, stream>>>(Qr, Kr, Vt, mp, Ar);
  mfma_gemm_kernel<2, true, true>
      <<<dim3(8, 32), blk, 0, stream>>>(Ar, Wob, nullptr, nullptr, out);
}

// Round 8
// 292.387 us; speedup vs baseline: 1.2764x; 1.1289x over previous
//
#include <hip/hip_runtime.h>
#include <hip/hip_bf16.h>

#define BB 2
#define SS 2048
#define DIMM 1024
#define HH 16
#define DKK 64
// 0.125 (1/sqrt(DK)) * log2(e): folded into Q so softmax uses raw v_exp_f32 (2^x)
#define QSCALE 0.18033688011112042592f

using bf16 = __hip_bfloat16;
typedef __attribute__((ext_vector_type(8))) short v8s;
typedef __attribute__((ext_vector_type(4))) short v4s;
typedef __attribute__((ext_vector_type(4))) float f32x4;

__device__ __forceinline__ void cvt4(const float* __restrict__ s,
                                     bf16* __restrict__ d, int idx) {
  const float4 f = ((const float4*)s)[idx];
  bf16 t[4] = {__float2bfloat16(f.x), __float2bfloat16(f.y),
               __float2bfloat16(f.z), __float2bfloat16(f.w)};
  *(v4s*)(d + (size_t)idx * 4) = *(const v4s*)t;
}

// ---------------------------------------------------------------------------
// Fused fp32->bf16 conversion (enc, Wkv, Wo) + mask bit-packing.
// ---------------------------------------------------------------------------
__global__ __launch_bounds__(256) void convert_pack_kernel(
    const float* __restrict__ enc, const float* __restrict__ Wkv,
    const float* __restrict__ Wo, const int* __restrict__ mask,
    bf16* __restrict__ encb, bf16* __restrict__ Wkvb, bf16* __restrict__ Wob,
    unsigned long long* __restrict__ mp) {
  const int gid = blockIdx.x * 256 + threadIdx.x;  // 0..262143
  const int NT = 256 * 1024;
#pragma unroll
  for (int i = 0; i < 4; ++i) cvt4(enc, encb, gid + i * NT);
#pragma unroll
  for (int i = 0; i < 2; ++i) cvt4(Wkv, Wkvb, gid + i * NT);
  cvt4(Wo, Wob, gid);
  const int lane = threadIdx.x & 63;
  const int wave_id = gid >> 6;  // 0..4095
  for (int i = 0; i < 32; ++i) {
    const size_t w = (size_t)wave_id * 32 + i;
    const unsigned long long bm = __ballot(mask[w * 64 + lane] != 0);
    if (lane == 0) mp[w] = bm;
  }
}

// ---------------------------------------------------------------------------
// Merged projection GEMM. Tile 128m x 64n, BK=64, reg-double-buffered.
// Grid (48, 32): bx<16 -> Q (W=Wq fp32, out Qr flat [b,s,h,d] *QSCALE);
// bx in [16,32) -> K half (W=Wkvb, out Kr flat); [32,48) -> V half
// (out Vt [b,h,d,s] scatter).  W rows are index-permuted so output col
// n' = h*64+d (head-contiguous) => coalesced Q/K stores.
// ---------------------------------------------------------------------------
template <bool ISQ>
__device__ __forceinline__ void proj_body(
    int t, int m0, int h0, bool isV, const float* __restrict__ dec,
    const bf16* __restrict__ encb, const float* __restrict__ Wq,
    const bf16* __restrict__ Wkvb, bf16 (*__restrict__ As)[72],
    bf16 (*__restrict__ Bs)[72], f32x4 (&acc)[4][2], int wm, int wn, int quad,
    int l15) {
  const int sr = t >> 2;        // 0..63
  const int sc = (t & 3) * 16;  // 0/16/32/48
  const int worig = (isV ? DIMM : 0) + sr * 16 + h0;  // permuted W row

  float4 aqf[8], bqf[4];
  v8s akb[4], bkb[2];

  auto loadA = [&](int kc) {
    if (ISQ) {
#pragma unroll
      for (int rr = 0; rr < 2; ++rr) {
        const float* p = dec + (size_t)(m0 + sr + rr * 64) * DIMM + kc + sc;
#pragma unroll
        for (int i = 0; i < 4; ++i) aqf[rr * 4 + i] = ((const float4*)p)[i];
      }
    } else {
#pragma unroll
      for (int rr = 0; rr < 2; ++rr) {
        const bf16* p = encb + (size_t)(m0 + sr + rr * 64) * DIMM + kc + sc;
#pragma unroll
        for (int i = 0; i < 2; ++i) akb[rr * 2 + i] = ((const v8s*)p)[i];
      }
    }
  };
  auto loadB = [&](int kc) {
    if (ISQ) {
      const float* p = Wq + (size_t)worig * DIMM + kc + sc;
#pragma unroll
      for (int i = 0; i < 4; ++i) bqf[i] = ((const float4*)p)[i];
    } else {
      const bf16* p = Wkvb + (size_t)worig * DIMM + kc + sc;
#pragma unroll
      for (int i = 0; i < 2; ++i) bkb[i] = ((const v8s*)p)[i];
    }
  };

  loadA(0);
  loadB(0);

  for (int kc = 0; kc < DIMM; kc += 64) {
    __syncthreads();
    if (ISQ) {
#pragma unroll
      for (int rr = 0; rr < 2; ++rr) {
        bf16 tmp[16];
#pragma unroll
        for (int i = 0; i < 4; ++i) {
          const float4 f = aqf[rr * 4 + i];
          tmp[i * 4 + 0] = __float2bfloat16(f.x);
          tmp[i * 4 + 1] = __float2bfloat16(f.y);
          tmp[i * 4 + 2] = __float2bfloat16(f.z);
          tmp[i * 4 + 3] = __float2bfloat16(f.w);
        }
        *(v8s*)&As[sr + rr * 64][sc] = *(const v8s*)&tmp[0];
        *(v8s*)&As[sr + rr * 64][sc + 8] = *(const v8s*)&tmp[8];
      }
      bf16 tb[16];
#pragma unroll
      for (int i = 0; i < 4; ++i) {
        const float4 f = bqf[i];
        tb[i * 4 + 0] = __float2bfloat16(f.x);
        tb[i * 4 + 1] = __float2bfloat16(f.y);
        tb[i * 4 + 2] = __float2bfloat16(f.z);
        tb[i * 4 + 3] = __float2bfloat16(f.w);
      }
      *(v8s*)&Bs[sr][sc] = *(const v8s*)&tb[0];
      *(v8s*)&Bs[sr][sc + 8] = *(const v8s*)&tb[8];
    } else {
#pragma unroll
      for (int rr = 0; rr < 2; ++rr) {
        *(v8s*)&As[sr + rr * 64][sc] = akb[rr * 2 + 0];
        *(v8s*)&As[sr + rr * 64][sc + 8] = akb[rr * 2 + 1];
      }
      *(v8s*)&Bs[sr][sc] = bkb[0];
      *(v8s*)&Bs[sr][sc + 8] = bkb[1];
    }
    if (kc + 64 < DIMM) {
      loadA(kc + 64);
      loadB(kc + 64);
    }
    __syncthreads();
#pragma unroll
    for (int ks = 0; ks < 2; ++ks) {
      v8s af[4], bfr[2];
#pragma unroll
      for (int i = 0; i < 4; ++i)
        af[i] = *(const v8s*)&As[wm + i * 16 + l15][ks * 32 + quad * 8];
#pragma unroll
      for (int j = 0; j < 2; ++j)
        bfr[j] = *(const v8s*)&Bs[wn + j * 16 + l15][ks * 32 + quad * 8];
#pragma unroll
      for (int i = 0; i < 4; ++i)
#pragma unroll
        for (int j = 0; j < 2; ++j)
          acc[i][j] = __builtin_amdgcn_mfma_f32_16x16x32_bf16(
              af[i], bfr[j], acc[i][j], 0, 0, 0);
    }
  }
}

__global__ __launch_bounds__(256) void proj_gemm_kernel(
    const float* __restrict__ dec, const bf16* __restrict__ encb,
    const float* __restrict__ Wq, const bf16* __restrict__ Wkvb,
    bf16* __restrict__ Qr, bf16* __restrict__ Kr, bf16* __restrict__ Vt) {
  __shared__ __align__(16) bf16 As[128][72];
  __shared__ __align__(16) bf16 Bs[64][72];
  const int t = threadIdx.x;
  const int wave = t >> 6, lane = t & 63;
  const int quad = lane >> 4, l15 = lane & 15;
  const int wm = (wave >> 1) * 64, wn = (wave & 1) * 32;
  const int bx = blockIdx.x;
  const int m0 = blockIdx.y * 128;
  const bool isQ = bx < 16;
  const int kvx = bx - 16;                 // 0..31 when KV
  const int h0 = isQ ? bx : (kvx & 15);
  const bool isV = !isQ && (kvx >= 16);

  f32x4 acc[4][2] = {};
  if (isQ)
    proj_body<true>(t, m0, h0, false, dec, encb, Wq, Wkvb, As, Bs, acc, wm, wn,
                    quad, l15);
  else
    proj_body<false>(t, m0, h0, isV, dec, encb, Wq, Wkvb, As, Bs, acc, wm, wn,
                     quad, l15);

#pragma unroll
  for (int i = 0; i < 4; ++i) {
#pragma unroll
    for (int r = 0; r < 4; ++r) {
      const int m = m0 + wm + i * 16 + quad * 4 + r;
#pragma unroll
      for (int j = 0; j < 2; ++j) {
        const int d = wn + j * 16 + l15;  // 0..63
        const float v = acc[i][j][r];
        if (isQ) {
          Qr[(size_t)m * DIMM + h0 * 64 + d] = __float2bfloat16(v * QSCALE);
        } else if (!isV) {
          Kr[(size_t)m * DIMM + h0 * 64 + d] = __float2bfloat16(v);
        } else {
          const int b = m >> 11, s = m & (SS - 1);
          Vt[(((size_t)b * HH + h0) * DKK + d) * SS + s] = __float2bfloat16(v);
        }
      }
    }
  }
}

// ---------------------------------------------------------------------------
// Output projection GEMM: out = Ar @ Wob^T. Tile 128m x 64n, BK=64, dbuf.
// Ar bf16 [4096,1024] (interleaved cols matching Wob cols), out fp32 flat.
// ---------------------------------------------------------------------------
__global__ __launch_bounds__(256) void out_gemm_kernel(
    const bf16* __restrict__ A, const bf16* __restrict__ W,
    float* __restrict__ out) {
  __shared__ __align__(16) bf16 As[128][72];
  __shared__ __align__(16) bf16 Bs[64][72];
  const int t = threadIdx.x;
  const int wave = t >> 6, lane = t & 63;
  const int quad = lane >> 4, l15 = lane & 15;
  const int wm = (wave >> 1) * 64, wn = (wave & 1) * 32;
  const int n0 = blockIdx.x * 64;
  const int m0 = blockIdx.y * 128;
  const int sr = t >> 2;
  const int sc = (t & 3) * 16;

  v8s ar[4], br[2];
  auto loadA = [&](int kc) {
#pragma unroll
    for (int rr = 0; rr < 2; ++rr) {
      const bf16* p = A + (size_t)(m0 + sr + rr * 64) * DIMM + kc + sc;
#pragma unroll
      for (int i = 0; i < 2; ++i) ar[rr * 2 + i] = ((const v8s*)p)[i];
    }
  };
  auto loadB = [&](int kc) {
    const bf16* p = W + (size_t)(n0 + sr) * DIMM + kc + sc;
#pragma unroll
    for (int i = 0; i < 2; ++i) br[i] = ((const v8s*)p)[i];
  };

  f32x4 acc[4][2] = {};
  loadA(0);
  loadB(0);
  for (int kc = 0; kc < DIMM; kc += 64) {
    __syncthreads();
#pragma unroll
    for (int rr = 0; rr < 2; ++rr) {
      *(v8s*)&As[sr + rr * 64][sc] = ar[rr * 2 + 0];
      *(v8s*)&As[sr + rr * 64][sc + 8] = ar[rr * 2 + 1];
    }
    *(v8s*)&Bs[sr][sc] = br[0];
    *(v8s*)&Bs[sr][sc + 8] = br[1];
    if (kc + 64 < DIMM) {
      loadA(kc + 64);
      loadB(kc + 64);
    }
    __syncthreads();
#pragma unroll
    for (int ks = 0; ks < 2; ++ks) {
      v8s af[4], bfr[2];
#pragma unroll
      for (int i = 0; i < 4; ++i)
        af[i] = *(const v8s*)&As[wm + i * 16 + l15][ks * 32 + quad * 8];
#pragma unroll
      for (int j = 0; j < 2; ++j)
        bfr[j] = *(const v8s*)&Bs[wn + j * 16 + l15][ks * 32 + quad * 8];
#pragma unroll
      for (int i = 0; i < 4; ++i)
#pragma unroll
        for (int j = 0; j < 2; ++j)
          acc[i][j] = __builtin_amdgcn_mfma_f32_16x16x32_bf16(
              af[i], bfr[j], acc[i][j], 0, 0, 0);
    }
  }

#pragma unroll
  for (int i = 0; i < 4; ++i) {
#pragma unroll
    for (int r = 0; r < 4; ++r) {
      const int m = m0 + wm + i * 16 + quad * 4 + r;
#pragma unroll
      for (int j = 0; j < 2; ++j) {
        const int n = n0 + wn + j * 16 + l15;
        out[(size_t)m * DIMM + n] = acc[i][j][r];
      }
    }
  }
}

// ---------------------------------------------------------------------------
// MFMA flash attention (round-5 body). Q/K now flat [b,s,h,d]; Vt [b,h,d,s].
// Static-max softmax, packed u64 mask, XCD swizzle.
// Ar bf16 [B,S,DIM] (q, d*16+h) — matches Wob's natural columns.
// ---------------------------------------------------------------------------
__global__ __launch_bounds__(256) void attn_kernel(
    const bf16* __restrict__ Qr, const bf16* __restrict__ Kr,
    const bf16* __restrict__ Vt, const unsigned long long* __restrict__ mp,
    bf16* __restrict__ Ar) {
  __shared__ __align__(16) bf16 Ks[64][72];
  __shared__ __align__(16) bf16 Vs[64][72];  // Vs[d][kk]
  __shared__ __align__(16) bf16 Ps[4][16][72];

  const int t = threadIdx.x;
  const int wave = t >> 6, lane = t & 63;
  const int quad = lane >> 4, l15 = lane & 15;

  const int bx = blockIdx.x;
  const int xcd = bx & 7, j = bx >> 3;
  const int g = (xcd << 2) | (j & 3);  // (b,h) group 0..31
  const int tile = j >> 2;             // q-tile 0..31
  const int h = g & 15, b = g >> 4;

  const int qw = tile * 64 + wave * 16;
  const size_t bhv = ((size_t)b * HH + h) * DKK;

  const bf16* qrow = Qr + ((size_t)(b * SS + qw + l15)) * DIMM + h * 64;
  const v8s aq0 = *(const v8s*)(qrow + quad * 8);
  const v8s aq1 = *(const v8s*)(qrow + 32 + quad * 8);

  f32x4 o[4] = {};
  float lsum[4] = {0.f, 0.f, 0.f, 0.f};

  const int id0 = t * 8;
  const int r0 = id0 >> 6, c0 = id0 & 63;

  for (int kt = 0; kt < 32; ++kt) {
    const int k0 = kt * 64;
    __syncthreads();
    {
      const bf16* kb = Kr + ((size_t)(b * SS + k0 + r0)) * DIMM + h * 64 + c0;
      *(v8s*)&Ks[r0][c0] = *(const v8s*)kb;
      *(v8s*)&Ks[r0 + 32][c0] = *(const v8s*)(kb + (size_t)32 * DIMM);
      *(v8s*)&Vs[r0][c0] = *(const v8s*)(Vt + (bhv + r0) * SS + k0 + c0);
      *(v8s*)&Vs[r0 + 32][c0] =
          *(const v8s*)(Vt + (bhv + r0 + 32) * SS + k0 + c0);
    }
    __syncthreads();

    f32x4 sc[4];
#pragma unroll
    for (int n = 0; n < 4; ++n) {
      const v8s bk0 = *(const v8s*)&Ks[n * 16 + l15][quad * 8];
      const v8s bk1 = *(const v8s*)&Ks[n * 16 + l15][32 + quad * 8];
      f32x4 z = {0.f, 0.f, 0.f, 0.f};
      z = __builtin_amdgcn_mfma_f32_16x16x32_bf16(aq0, bk0, z, 0, 0, 0);
      sc[n] = __builtin_amdgcn_mfma_f32_16x16x32_bf16(aq1, bk1, z, 0, 0, 0);
    }

    unsigned long long mw[4];
#pragma unroll
    for (int r = 0; r < 4; ++r)
      mw[r] = mp[((size_t)b * SS + qw + quad * 4 + r) * 32 + kt];
#pragma unroll
    for (int n = 0; n < 4; ++n)
#pragma unroll
      for (int r = 0; r < 4; ++r) {
        const bool keep = (mw[r] >> (n * 16 + l15)) & 1ULL;
        const float p = keep ? __builtin_amdgcn_exp2f(sc[n][r]) : 0.f;
        sc[n][r] = p;
        lsum[r] += p;
      }

#pragma unroll
    for (int n = 0; n < 4; ++n)
#pragma unroll
      for (int r = 0; r < 4; ++r)
        Ps[wave][quad * 4 + r][n * 16 + l15] = __float2bfloat16(sc[n][r]);
    const v8s ap0 = *(const v8s*)&Ps[wave][l15][quad * 8];
    const v8s ap1 = *(const v8s*)&Ps[wave][l15][32 + quad * 8];

#pragma unroll
    for (int n = 0; n < 4; ++n) {
      const v8s bv0 = *(const v8s*)&Vs[n * 16 + l15][quad * 8];
      const v8s bv1 = *(const v8s*)&Vs[n * 16 + l15][32 + quad * 8];
      o[n] = __builtin_amdgcn_mfma_f32_16x16x32_bf16(ap0, bv0, o[n], 0, 0, 0);
      o[n] = __builtin_amdgcn_mfma_f32_16x16x32_bf16(ap1, bv1, o[n], 0, 0, 0);
    }
  }

#pragma unroll
  for (int r = 0; r < 4; ++r) {
    float l = lsum[r];
    l += __shfl_xor(l, 1);
    l += __shfl_xor(l, 2);
    l += __shfl_xor(l, 4);
    l += __shfl_xor(l, 8);
    const float inv = 1.f / l;
    const size_t row = (size_t)b * SS + qw + quad * 4 + r;
#pragma unroll
    for (int n = 0; n < 4; ++n) {
      const int d = n * 16 + l15;
      Ar[row * DIMM + d * 16 + h] = __float2bfloat16(o[n][r] * inv);
    }
  }
}

extern "C" void kernel_launch(void* const* d_in, const int* in_sizes, int n_in,
                              void* d_out, int out_size, void* d_ws,
                              size_t ws_size, hipStream_t stream) {
  const float* dec = (const float*)d_in[0];
  const float* enc = (const float*)d_in[1];
  const float* Wq = (const float*)d_in[2];
  const float* Wkv = (const float*)d_in[3];
  const float* Wo = (const float*)d_in[4];
  const int* mask = (const int*)d_in[5];
  float* out = (float*)d_out;

  // ws layout (40,894,464 B total — same proven footprint as round 7):
  //  encb 8 MiB (Ar overlays: encb dead after proj, Ar written by attn)
  //  Wkvb 4 MiB | Wob 2 MiB | Qr 8 MiB | Kr 8 MiB | Vt 8 MiB | mp 1 MiB
  char* ws = (char*)d_ws;
  size_t off = 0;
  bf16* encb = (bf16*)(ws + off);
  bf16* Ar = (bf16*)(ws + off);  off += (size_t)2 * SS * DIMM * 2;
  bf16* Wkvb = (bf16*)(ws + off); off += (size_t)2 * DIMM * DIMM * 2;
  bf16* Wob = (bf16*)(ws + off);  off += (size_t)DIMM * DIMM * 2;
  bf16* Qr = (bf16*)(ws + off);   off += (size_t)2 * SS * DIMM * 2;
  bf16* Kr = (bf16*)(ws + off);   off += (size_t)2 * SS * DIMM * 2;
  bf16* Vt = (bf16*)(ws + off);   off += (size_t)2 * SS * DIMM * 2;
  unsigned long long* mp = (unsigned long long*)(ws + off);

  dim3 blk(256);
  convert_pack_kernel<<<dim3(1024), blk, 0, stream>>>(enc, Wkv, Wo, mask, encb,
                                                      Wkvb, Wob, mp);
  proj_gemm_kernel<<<dim3(48, 32), blk, 0, stream>>>(dec, encb, Wq, Wkvb, Qr,
                                                     Kr, Vt);
  attn_kernel<<<dim3(1024), blk, 0, stream>>>(Qr, Kr, Vt, mp, Ar);
  out_gemm_kernel<<<dim3(16, 32), blk, 0, stream>>>(Ar, Wob, out);
}

// Round 9
// 286.835 us; speedup vs baseline: 1.3011x; 1.0194x over previous
//
#include <hip/hip_runtime.h>
#include <hip/hip_bf16.h>

#define BB 2
#define SS 2048
#define DIMM 1024
#define HH 16
#define DKK 64
// 0.125 (1/sqrt(DK)) * log2(e): folded into Q so softmax uses raw v_exp_f32 (2^x)
#define QSCALE 0.18033688011112042592f

using bf16 = __hip_bfloat16;
typedef __attribute__((ext_vector_type(8))) short v8s;
typedef __attribute__((ext_vector_type(4))) short v4s;
typedef __attribute__((ext_vector_type(4))) float f32x4;

__device__ __forceinline__ void cvt4(const float* __restrict__ s,
                                     bf16* __restrict__ d, int idx) {
  const float4 f = ((const float4*)s)[idx];
  bf16 t[4] = {__float2bfloat16(f.x), __float2bfloat16(f.y),
               __float2bfloat16(f.z), __float2bfloat16(f.w)};
  *(v4s*)(d + (size_t)idx * 4) = *(const v4s*)t;
}

// ---------------------------------------------------------------------------
// Fused fp32->bf16 conversion (dec, enc, Wq, Wkv, Wo) + mask bit-packing.
// decb/Wqb live in d_out (dead scratch until out_gemm overwrites it).
// ---------------------------------------------------------------------------
__global__ __launch_bounds__(256) void convert_pack_kernel(
    const float* __restrict__ dec, const float* __restrict__ enc,
    const float* __restrict__ Wq, const float* __restrict__ Wkv,
    const float* __restrict__ Wo, const int* __restrict__ mask,
    bf16* __restrict__ decb, bf16* __restrict__ encb, bf16* __restrict__ Wqb,
    bf16* __restrict__ Wkvb, bf16* __restrict__ Wob,
    unsigned long long* __restrict__ mp) {
  const int gid = blockIdx.x * 256 + threadIdx.x;  // 0..262143
  const int NT = 256 * 1024;
#pragma unroll
  for (int i = 0; i < 4; ++i) cvt4(dec, decb, gid + i * NT);
#pragma unroll
  for (int i = 0; i < 4; ++i) cvt4(enc, encb, gid + i * NT);
  cvt4(Wq, Wqb, gid);
#pragma unroll
  for (int i = 0; i < 2; ++i) cvt4(Wkv, Wkvb, gid + i * NT);
  cvt4(Wo, Wob, gid);
  const int lane = threadIdx.x & 63;
  const int wave_id = gid >> 6;  // 0..4095
  for (int i = 0; i < 32; ++i) {
    const size_t w = (size_t)wave_id * 32 + i;
    const unsigned long long bm = __ballot(mask[w * 64 + lane] != 0);
    if (lane == 0) mp[w] = bm;
  }
}

// ---------------------------------------------------------------------------
// Merged projection GEMM, uniform bf16. Tile 128m x 128n, BK=64, reg-dbuf.
// Grid (24, 32): bx>>3 = 0 -> Q (A=decb, W=Wqb), 1 -> K, 2 -> V (A=encb,
// W=Wkvb[+1024]).  W rows index-permuted so output col n' = h*64+d:
// tile row r (0..127) of group g stages W row (r&63)*16 + g*2 + (r>>6).
// Q/K store flat [b,s,h,d] coalesced (Q prescaled); V scatters to [b,h,d,s].
// ---------------------------------------------------------------------------
__global__ __launch_bounds__(256) void proj_gemm_kernel(
    const bf16* __restrict__ decb, const bf16* __restrict__ encb,
    const bf16* __restrict__ Wqb, const bf16* __restrict__ Wkvb,
    bf16* __restrict__ Qr, bf16* __restrict__ Kr, bf16* __restrict__ Vt) {
  __shared__ __align__(16) bf16 As[128][72];
  __shared__ __align__(16) bf16 Bs[128][72];
  const int t = threadIdx.x;
  const int wave = t >> 6, lane = t & 63;
  const int quad = lane >> 4, l15 = lane & 15;
  const int wm = (wave >> 1) * 64, wn = (wave & 1) * 64;
  const int bx = blockIdx.x;
  const int kind = bx >> 3;  // 0=Q, 1=K, 2=V
  const int g = bx & 7;      // 128-col group (2 heads)
  const int m0 = blockIdx.y * 128;

  const bf16* Asrc = (kind == 0) ? decb : encb;
  const bf16* Wsrc = (kind == 0) ? Wqb : Wkvb;

  const int sr = t >> 2;        // staging row 0..63 (and +64)
  const int sc = (t & 3) * 16;  // staging col segment
  const int wr0 = sr * 16 + g * 2 + ((kind == 2) ? DIMM : 0);      // row sr
  const int wr1 = sr * 16 + g * 2 + 1 + ((kind == 2) ? DIMM : 0);  // row sr+64

  v8s apf[4], bpf[4];
  auto loadA = [&](int kc) {
    const bf16* p0 = Asrc + (size_t)(m0 + sr) * DIMM + kc + sc;
    apf[0] = ((const v8s*)p0)[0];
    apf[1] = ((const v8s*)p0)[1];
    const bf16* p1 = Asrc + (size_t)(m0 + sr + 64) * DIMM + kc + sc;
    apf[2] = ((const v8s*)p1)[0];
    apf[3] = ((const v8s*)p1)[1];
  };
  auto loadB = [&](int kc) {
    const bf16* q0 = Wsrc + (size_t)wr0 * DIMM + kc + sc;
    bpf[0] = ((const v8s*)q0)[0];
    bpf[1] = ((const v8s*)q0)[1];
    const bf16* q1 = Wsrc + (size_t)wr1 * DIMM + kc + sc;
    bpf[2] = ((const v8s*)q1)[0];
    bpf[3] = ((const v8s*)q1)[1];
  };

  f32x4 acc[4][4] = {};
  loadA(0);
  loadB(0);

  for (int kc = 0; kc < DIMM; kc += 64) {
    __syncthreads();
    *(v8s*)&As[sr][sc] = apf[0];
    *(v8s*)&As[sr][sc + 8] = apf[1];
    *(v8s*)&As[sr + 64][sc] = apf[2];
    *(v8s*)&As[sr + 64][sc + 8] = apf[3];
    *(v8s*)&Bs[sr][sc] = bpf[0];
    *(v8s*)&Bs[sr][sc + 8] = bpf[1];
    *(v8s*)&Bs[sr + 64][sc] = bpf[2];
    *(v8s*)&Bs[sr + 64][sc + 8] = bpf[3];
    if (kc + 64 < DIMM) {
      loadA(kc + 64);
      loadB(kc + 64);
    }
    __syncthreads();
#pragma unroll
    for (int ks = 0; ks < 2; ++ks) {
      v8s af[4], bfr[4];
#pragma unroll
      for (int i = 0; i < 4; ++i)
        af[i] = *(const v8s*)&As[wm + i * 16 + l15][ks * 32 + quad * 8];
#pragma unroll
      for (int j = 0; j < 4; ++j)
        bfr[j] = *(const v8s*)&Bs[wn + j * 16 + l15][ks * 32 + quad * 8];
#pragma unroll
      for (int i = 0; i < 4; ++i)
#pragma unroll
        for (int j = 0; j < 4; ++j)
          acc[i][j] = __builtin_amdgcn_mfma_f32_16x16x32_bf16(
              af[i], bfr[j], acc[i][j], 0, 0, 0);
    }
  }

#pragma unroll
  for (int i = 0; i < 4; ++i) {
#pragma unroll
    for (int r = 0; r < 4; ++r) {
      const int m = m0 + wm + i * 16 + quad * 4 + r;
#pragma unroll
      for (int j = 0; j < 4; ++j) {
        const int c = wn + j * 16 + l15;
        const int np = g * 128 + c;  // head-contiguous col h*64+d
        const float v = acc[i][j][r];
        if (kind == 0) {
          Qr[(size_t)m * DIMM + np] = __float2bfloat16(v * QSCALE);
        } else if (kind == 1) {
          Kr[(size_t)m * DIMM + np] = __float2bfloat16(v);
        } else {
          const int h = np >> 6, d = np & 63;
          const int b = m >> 11, s = m & (SS - 1);
          Vt[(((size_t)b * HH + h) * DKK + d) * SS + s] = __float2bfloat16(v);
        }
      }
    }
  }
}

// ---------------------------------------------------------------------------
// Output projection GEMM: out = Ar @ Wob^T. Tile 128m x 64n, BK=64, dbuf.
// ---------------------------------------------------------------------------
__global__ __launch_bounds__(256) void out_gemm_kernel(
    const bf16* __restrict__ A, const bf16* __restrict__ W,
    float* __restrict__ out) {
  __shared__ __align__(16) bf16 As[128][72];
  __shared__ __align__(16) bf16 Bs[64][72];
  const int t = threadIdx.x;
  const int wave = t >> 6, lane = t & 63;
  const int quad = lane >> 4, l15 = lane & 15;
  const int wm = (wave >> 1) * 64, wn = (wave & 1) * 32;
  const int n0 = blockIdx.x * 64;
  const int m0 = blockIdx.y * 128;
  const int sr = t >> 2;
  const int sc = (t & 3) * 16;

  v8s ar[4], br[2];
  auto loadA = [&](int kc) {
#pragma unroll
    for (int rr = 0; rr < 2; ++rr) {
      const bf16* p = A + (size_t)(m0 + sr + rr * 64) * DIMM + kc + sc;
#pragma unroll
      for (int i = 0; i < 2; ++i) ar[rr * 2 + i] = ((const v8s*)p)[i];
    }
  };
  auto loadB = [&](int kc) {
    const bf16* p = W + (size_t)(n0 + sr) * DIMM + kc + sc;
#pragma unroll
    for (int i = 0; i < 2; ++i) br[i] = ((const v8s*)p)[i];
  };

  f32x4 acc[4][2] = {};
  loadA(0);
  loadB(0);
  for (int kc = 0; kc < DIMM; kc += 64) {
    __syncthreads();
#pragma unroll
    for (int rr = 0; rr < 2; ++rr) {
      *(v8s*)&As[sr + rr * 64][sc] = ar[rr * 2 + 0];
      *(v8s*)&As[sr + rr * 64][sc + 8] = ar[rr * 2 + 1];
    }
    *(v8s*)&Bs[sr][sc] = br[0];
    *(v8s*)&Bs[sr][sc + 8] = br[1];
    if (kc + 64 < DIMM) {
      loadA(kc + 64);
      loadB(kc + 64);
    }
    __syncthreads();
#pragma unroll
    for (int ks = 0; ks < 2; ++ks) {
      v8s af[4], bfr[2];
#pragma unroll
      for (int i = 0; i < 4; ++i)
        af[i] = *(const v8s*)&As[wm + i * 16 + l15][ks * 32 + quad * 8];
#pragma unroll
      for (int j = 0; j < 2; ++j)
        bfr[j] = *(const v8s*)&Bs[wn + j * 16 + l15][ks * 32 + quad * 8];
#pragma unroll
      for (int i = 0; i < 4; ++i)
#pragma unroll
        for (int j = 0; j < 2; ++j)
          acc[i][j] = __builtin_amdgcn_mfma_f32_16x16x32_bf16(
              af[i], bfr[j], acc[i][j], 0, 0, 0);
    }
  }

#pragma unroll
  for (int i = 0; i < 4; ++i) {
#pragma unroll
    for (int r = 0; r < 4; ++r) {
      const int m = m0 + wm + i * 16 + quad * 4 + r;
#pragma unroll
      for (int j = 0; j < 2; ++j) {
        const int n = n0 + wn + j * 16 + l15;
        out[(size_t)m * DIMM + n] = acc[i][j][r];
      }
    }
  }
}

// ---------------------------------------------------------------------------
// MFMA flash attention. Q/K flat [b,s,h,d]; Vt [b,h,d,s]. Static-max softmax,
// packed u64 mask (pre-shifted by l15 -> constant-shift bit extraction),
// XCD swizzle.  Ar bf16 [B,S,DIM] (q, d*16+h).
// ---------------------------------------------------------------------------
__global__ __launch_bounds__(256) void attn_kernel(
    const bf16* __restrict__ Qr, const bf16* __restrict__ Kr,
    const bf16* __restrict__ Vt, const unsigned long long* __restrict__ mp,
    bf16* __restrict__ Ar) {
  __shared__ __align__(16) bf16 Ks[64][72];
  __shared__ __align__(16) bf16 Vs[64][72];  // Vs[d][kk]
  __shared__ __align__(16) bf16 Ps[4][16][72];

  const int t = threadIdx.x;
  const int wave = t >> 6, lane = t & 63;
  const int quad = lane >> 4, l15 = lane & 15;

  const int bx = blockIdx.x;
  const int xcd = bx & 7, j = bx >> 3;
  const int g = (xcd << 2) | (j & 3);  // (b,h) group 0..31
  const int tile = j >> 2;             // q-tile 0..31
  const int h = g & 15, b = g >> 4;

  const int qw = tile * 64 + wave * 16;
  const size_t bhv = ((size_t)b * HH + h) * DKK;

  const bf16* qrow = Qr + ((size_t)(b * SS + qw + l15)) * DIMM + h * 64;
  const v8s aq0 = *(const v8s*)(qrow + quad * 8);
  const v8s aq1 = *(const v8s*)(qrow + 32 + quad * 8);

  f32x4 o[4] = {};
  float lsum[4] = {0.f, 0.f, 0.f, 0.f};

  const int id0 = t * 8;
  const int r0 = id0 >> 6, c0 = id0 & 63;

  for (int kt = 0; kt < 32; ++kt) {
    const int k0 = kt * 64;
    __syncthreads();
    {
      const bf16* kb = Kr + ((size_t)(b * SS + k0 + r0)) * DIMM + h * 64 + c0;
      *(v8s*)&Ks[r0][c0] = *(const v8s*)kb;
      *(v8s*)&Ks[r0 + 32][c0] = *(const v8s*)(kb + (size_t)32 * DIMM);
      *(v8s*)&Vs[r0][c0] = *(const v8s*)(Vt + (bhv + r0) * SS + k0 + c0);
      *(v8s*)&Vs[r0 + 32][c0] =
          *(const v8s*)(Vt + (bhv + r0 + 32) * SS + k0 + c0);
    }
    __syncthreads();

    // mask words issued early (latency shadowed by QK MFMAs); pre-shift by
    // l15 so per-element extraction is a constant shift.
    unsigned long long mw[4];
#pragma unroll
    for (int r = 0; r < 4; ++r)
      mw[r] = mp[((size_t)b * SS + qw + quad * 4 + r) * 32 + kt] >> l15;

    f32x4 sc[4];
#pragma unroll
    for (int n = 0; n < 4; ++n) {
      const v8s bk0 = *(const v8s*)&Ks[n * 16 + l15][quad * 8];
      const v8s bk1 = *(const v8s*)&Ks[n * 16 + l15][32 + quad * 8];
      f32x4 z = {0.f, 0.f, 0.f, 0.f};
      z = __builtin_amdgcn_mfma_f32_16x16x32_bf16(aq0, bk0, z, 0, 0, 0);
      sc[n] = __builtin_amdgcn_mfma_f32_16x16x32_bf16(aq1, bk1, z, 0, 0, 0);
    }

#pragma unroll
    for (int n = 0; n < 4; ++n)
#pragma unroll
      for (int r = 0; r < 4; ++r) {
        const bool keep = (mw[r] >> (n * 16)) & 1ULL;
        const float p = keep ? __builtin_amdgcn_exp2f(sc[n][r]) : 0.f;
        sc[n][r] = p;
        lsum[r] += p;
      }

    // P: C-layout -> LDS -> A-layout (per-wave region, in-wave dependency)
#pragma unroll
    for (int n = 0; n < 4; ++n)
#pragma unroll
      for (int r = 0; r < 4; ++r)
        Ps[wave][quad * 4 + r][n * 16 + l15] = __float2bfloat16(sc[n][r]);
    const v8s ap0 = *(const v8s*)&Ps[wave][l15][quad * 8];
    const v8s ap1 = *(const v8s*)&Ps[wave][l15][32 + quad * 8];

#pragma unroll
    for (int n = 0; n < 4; ++n) {
      const v8s bv0 = *(const v8s*)&Vs[n * 16 + l15][quad * 8];
      const v8s bv1 = *(const v8s*)&Vs[n * 16 + l15][32 + quad * 8];
      o[n] = __builtin_amdgcn_mfma_f32_16x16x32_bf16(ap0, bv0, o[n], 0, 0, 0);
      o[n] = __builtin_amdgcn_mfma_f32_16x16x32_bf16(ap1, bv1, o[n], 0, 0, 0);
    }
  }

#pragma unroll
  for (int r = 0; r < 4; ++r) {
    float l = lsum[r];
    l += __shfl_xor(l, 1);
    l += __shfl_xor(l, 2);
    l += __shfl_xor(l, 4);
    l += __shfl_xor(l, 8);
    const float inv = 1.f / l;
    const size_t row = (size_t)b * SS + qw + quad * 4 + r;
#pragma unroll
    for (int n = 0; n < 4; ++n) {
      const int d = n * 16 + l15;
      Ar[row * DIMM + d * 16 + h] = __float2bfloat16(o[n][r] * inv);
    }
  }
}

extern "C" void kernel_launch(void* const* d_in, const int* in_sizes, int n_in,
                              void* d_out, int out_size, void* d_ws,
                              size_t ws_size, hipStream_t stream) {
  const float* dec = (const float*)d_in[0];
  const float* enc = (const float*)d_in[1];
  const float* Wq = (const float*)d_in[2];
  const float* Wkv = (const float*)d_in[3];
  const float* Wo = (const float*)d_in[4];
  const int* mask = (const int*)d_in[5];
  float* out = (float*)d_out;

  // decb/Wqb live in d_out: it is dead scratch until out_gemm (the final
  // kernel) overwrites all 16.8 MB.  decb 8 MiB + Wqb 2 MiB <= 16.8 MiB.
  bf16* decb = (bf16*)d_out;
  bf16* Wqb = (bf16*)((char*)d_out + ((size_t)2 * SS * DIMM * 2));

  // ws layout (40.4 MB, same proven footprint):
  //  encb 8 MiB (Ar overlays: encb dead after proj, Ar written by attn)
  //  Wkvb 4 MiB | Wob 2 MiB | Qr 8 MiB | Kr 8 MiB | Vt 8 MiB | mp 1 MiB
  char* ws = (char*)d_ws;
  size_t off = 0;
  bf16* encb = (bf16*)(ws + off);
  bf16* Ar = (bf16*)(ws + off);   off += (size_t)2 * SS * DIMM * 2;
  bf16* Wkvb = (bf16*)(ws + off); off += (size_t)2 * DIMM * DIMM * 2;
  bf16* Wob = (bf16*)(ws + off);  off += (size_t)DIMM * DIMM * 2;
  bf16* Qr = (bf16*)(ws + off);   off += (size_t)2 * SS * DIMM * 2;
  bf16* Kr = (bf16*)(ws + off);   off += (size_t)2 * SS * DIMM * 2;
  bf16* Vt = (bf16*)(ws + off);   off += (size_t)2 * SS * DIMM * 2;
  unsigned long long* mp = (unsigned long long*)(ws + off);

  dim3 blk(256);
  convert_pack_kernel<<<dim3(1024), blk, 0, stream>>>(
      dec, enc, Wq, Wkv, Wo, mask, decb, encb, Wqb, Wkvb, Wob, mp);
  proj_gemm_kernel<<<dim3(24, 32), blk, 0, stream>>>(decb, encb, Wqb, Wkvb, Qr,
                                                     Kr, Vt);
  attn_kernel<<<dim3(1024), blk, 0, stream>>>(Qr, Kr, Vt, mp, Ar);
  out_gemm_kernel<<<dim3(16, 32), blk, 0, stream>>>(Ar, Wob, out);
}